// Round 1
// baseline (2136.626 us; speedup 1.0000x reference)
//
#include <hip/hip_runtime.h>

#define NN     100000
#define EE     3200000
#define NF     512
#define HIDN   64
#define NCLS   64
#define ALPHA  0.1f

// ---------------------------------------------------------------------------
// Tiled fp32 GEMM: C[nrows x 64] = act(A[nrows x K] @ B[K x 64])
// 64x64 tile per block, BK=16, 256 threads, 4x4 micro-tile, float4 LDS reads.
// RELU: apply relu. DUP: also write C2 (used to init z = z0).
// ---------------------------------------------------------------------------
template <bool RELU, bool DUP>
__global__ __launch_bounds__(256) void gemm_kernel(
    const float* __restrict__ A, const float* __restrict__ B,
    float* __restrict__ C, float* __restrict__ C2, int nrows, int K)
{
    const int BK = 16;
    __shared__ float AsT[BK][68];  // [k][row], padded stride 68 (16B-aligned, conflict-light)
    __shared__ float Bs [BK][68];  // [k][col]

    int tid = threadIdx.x;
    int tx  = tid & 15;            // col group (4 cols each)
    int ty  = tid >> 4;            // row group (4 rows each)
    int rowBase = blockIdx.x * 64;

    // global-load assignments
    int arow = tid >> 2;           // 0..63
    int ak   = (tid & 3) * 4;      // 0,4,8,12
    int brow = tid >> 4;           // 0..15
    int bcol = (tid & 15) * 4;     // 0..60

    float acc[4][4] = {};

    for (int k0 = 0; k0 < K; k0 += BK) {
        float4 av;
        int gr = rowBase + arow;
        if (gr < nrows) av = *(const float4*)(A + (size_t)gr * K + k0 + ak);
        else            av = make_float4(0.f, 0.f, 0.f, 0.f);
        float4 bv = *(const float4*)(B + (size_t)(k0 + brow) * 64 + bcol);

        __syncthreads();           // protect previous iteration's LDS reads
        AsT[ak + 0][arow] = av.x;
        AsT[ak + 1][arow] = av.y;
        AsT[ak + 2][arow] = av.z;
        AsT[ak + 3][arow] = av.w;
        *(float4*)&Bs[brow][bcol] = bv;
        __syncthreads();

#pragma unroll
        for (int kk = 0; kk < BK; ++kk) {
            float4 a = *(const float4*)&AsT[kk][ty * 4];
            float4 b = *(const float4*)&Bs [kk][tx * 4];
            acc[0][0] = fmaf(a.x, b.x, acc[0][0]);
            acc[0][1] = fmaf(a.x, b.y, acc[0][1]);
            acc[0][2] = fmaf(a.x, b.z, acc[0][2]);
            acc[0][3] = fmaf(a.x, b.w, acc[0][3]);
            acc[1][0] = fmaf(a.y, b.x, acc[1][0]);
            acc[1][1] = fmaf(a.y, b.y, acc[1][1]);
            acc[1][2] = fmaf(a.y, b.z, acc[1][2]);
            acc[1][3] = fmaf(a.y, b.w, acc[1][3]);
            acc[2][0] = fmaf(a.z, b.x, acc[2][0]);
            acc[2][1] = fmaf(a.z, b.y, acc[2][1]);
            acc[2][2] = fmaf(a.z, b.z, acc[2][2]);
            acc[2][3] = fmaf(a.z, b.w, acc[2][3]);
            acc[3][0] = fmaf(a.w, b.x, acc[3][0]);
            acc[3][1] = fmaf(a.w, b.y, acc[3][1]);
            acc[3][2] = fmaf(a.w, b.z, acc[3][2]);
            acc[3][3] = fmaf(a.w, b.w, acc[3][3]);
        }
    }

#pragma unroll
    for (int i = 0; i < 4; ++i) {
        int r = rowBase + ty * 4 + i;
        if (r < nrows) {
            float4 o;
            o.x = acc[i][0]; o.y = acc[i][1]; o.z = acc[i][2]; o.w = acc[i][3];
            if (RELU) {
                o.x = fmaxf(o.x, 0.f); o.y = fmaxf(o.y, 0.f);
                o.z = fmaxf(o.z, 0.f); o.w = fmaxf(o.w, 0.f);
            }
            *(float4*)(C + (size_t)r * 64 + tx * 4) = o;
            if (DUP) *(float4*)(C2 + (size_t)r * 64 + tx * 4) = o;
        }
    }
}

// ---------------------------------------------------------------------------
// CSR construction
// ---------------------------------------------------------------------------
__global__ __launch_bounds__(256) void zero_kernel(int* __restrict__ p, int n)
{
    int i = blockIdx.x * 256 + threadIdx.x;
    if (i < n) p[i] = 0;
}

__global__ __launch_bounds__(256) void count_kernel(const int* __restrict__ dst,
                                                    int* __restrict__ deg)
{
    int e = blockIdx.x * 256 + threadIdx.x;
    if (e < EE) atomicAdd(&deg[dst[e]], 1);
}

// single-block exclusive scan of deg[0..n) -> offs[0..n], cursor[0..n)
__global__ __launch_bounds__(1024) void scan_kernel(const int* __restrict__ deg,
                                                    int* __restrict__ offs,
                                                    int* __restrict__ cursor, int n)
{
    const int T = 1024;
    int tid = threadIdx.x;
    int items = (n + T - 1) / T;
    int beg = tid * items;
    int end = beg + items; if (end > n) end = n; if (beg > n) beg = n;

    int local = 0;
    for (int i = beg; i < end; ++i) local += deg[i];

    __shared__ int smem[T];
    smem[tid] = local;
    __syncthreads();
    for (int offset = 1; offset < T; offset <<= 1) {
        int t = 0;
        if (tid >= offset) t = smem[tid - offset];
        __syncthreads();
        if (tid >= offset) smem[tid] += t;
        __syncthreads();
    }
    int run = smem[tid] - local;   // exclusive prefix of this thread's chunk
    for (int i = beg; i < end; ++i) {
        int v = deg[i];
        offs[i] = run;
        cursor[i] = run;
        run += v;
    }
    if (tid == T - 1) offs[n] = run;
}

__global__ __launch_bounds__(256) void scatter_kernel(
    const int* __restrict__ src, const int* __restrict__ dst,
    const float* __restrict__ w, int* cursor,
    int* __restrict__ csr_src, float* __restrict__ csr_w)
{
    int e = blockIdx.x * 256 + threadIdx.x;
    if (e >= EE) return;
    int d = dst[e];
    int pos = atomicAdd(&cursor[d], 1);
    csr_src[pos] = src[e];
    csr_w[pos] = w[e];
}

// ---------------------------------------------------------------------------
// APPNP propagation: one wave per dst node, lane = class.
// z_new[n] = sum_{e in in(n)} w_e * z[src_e] + alpha * z0[n]
// ---------------------------------------------------------------------------
__global__ __launch_bounds__(256) void propagate_kernel(
    const float* __restrict__ zin, const float* __restrict__ z0,
    float* __restrict__ zout, const int* __restrict__ offs,
    const int* __restrict__ csr_src, const float* __restrict__ csr_w)
{
    int gid  = blockIdx.x * 256 + threadIdx.x;
    int node = gid >> 6;
    int lane = gid & 63;
    if (node >= NN) return;

    int beg = offs[node];
    int end = offs[node + 1];
    float acc = 0.f;
    int j = beg;
    for (; j + 4 <= end; j += 4) {
        int   s0 = csr_src[j],     s1 = csr_src[j + 1];
        int   s2 = csr_src[j + 2], s3 = csr_src[j + 3];
        float w0 = csr_w[j],       w1 = csr_w[j + 1];
        float w2 = csr_w[j + 2],   w3 = csr_w[j + 3];
        float v0 = zin[(size_t)s0 * 64 + lane];
        float v1 = zin[(size_t)s1 * 64 + lane];
        float v2 = zin[(size_t)s2 * 64 + lane];
        float v3 = zin[(size_t)s3 * 64 + lane];
        acc = fmaf(w0, v0, acc);
        acc = fmaf(w1, v1, acc);
        acc = fmaf(w2, v2, acc);
        acc = fmaf(w3, v3, acc);
    }
    for (; j < end; ++j)
        acc = fmaf(csr_w[j], zin[(size_t)csr_src[j] * 64 + lane], acc);

    zout[(size_t)node * 64 + lane] = fmaf(ALPHA, z0[(size_t)node * 64 + lane], acc);
}

// ---------------------------------------------------------------------------
// log_softmax over 64 classes, one wave per node, in-place.
// ---------------------------------------------------------------------------
__global__ __launch_bounds__(256) void logsoftmax_kernel(float* __restrict__ z)
{
    int gid  = blockIdx.x * 256 + threadIdx.x;
    int node = gid >> 6;
    int lane = gid & 63;
    if (node >= NN) return;

    float v = z[(size_t)node * 64 + lane];
    float m = v;
#pragma unroll
    for (int o = 32; o > 0; o >>= 1) m = fmaxf(m, __shfl_xor(m, o, 64));
    float e = __expf(v - m);
    float s = e;
#pragma unroll
    for (int o = 32; o > 0; o >>= 1) s += __shfl_xor(s, o, 64);
    z[(size_t)node * 64 + lane] = (v - m) - __logf(s);
}

// ---------------------------------------------------------------------------
extern "C" void kernel_launch(void* const* d_in, const int* in_sizes, int n_in,
                              void* d_out, int out_size, void* d_ws, size_t ws_size,
                              hipStream_t stream)
{
    const float* x  = (const float*)d_in[0];
    const int*   ei = (const int*)  d_in[1];
    const float* ew = (const float*)d_in[2];
    const float* W1 = (const float*)d_in[3];
    const float* W2 = (const float*)d_in[4];
    const int* src = ei;        // edge_index[0]
    const int* dst = ei + EE;   // edge_index[1]

    char* ws = (char*)d_ws;
    size_t off = 0;
    auto alloc = [&](size_t bytes) -> char* {
        char* p = ws + off;
        off += (bytes + 255) & ~(size_t)255;
        return p;
    };

    float* h    = (float*)alloc((size_t)NN * HIDN * 4);   // 25.6 MB; reused as CSR after GEMM2
    float* z0   = (float*)alloc((size_t)NN * NCLS * 4);
    float* zB   = (float*)alloc((size_t)NN * NCLS * 4);
    int*   deg  = (int*)  alloc((size_t)NN * 4);
    int*   offs = (int*)  alloc((size_t)(NN + 1) * 4);
    int*   cur_ = (int*)  alloc((size_t)NN * 4);

    int*   csr_src = (int*)h;                              // aliases h (h dead after GEMM2)
    float* csr_w   = (float*)((char*)h + (size_t)EE * 4);
    float* zA = (float*)d_out;

    // h = relu(x @ W1)
    gemm_kernel<true, false><<<(NN + 63) / 64, 256, 0, stream>>>(x, W1, h, nullptr, NN, NF);
    // z0 = h @ W2 ; z = z0
    gemm_kernel<false, true><<<(NN + 63) / 64, 256, 0, stream>>>(h, W2, z0, zA, NN, HIDN);

    // CSR by dst (h is dead from here; csr aliases it)
    zero_kernel<<<(NN + 255) / 256, 256, 0, stream>>>(deg, NN);
    count_kernel<<<EE / 256, 256, 0, stream>>>(dst, deg);
    scan_kernel<<<1, 1024, 0, stream>>>(deg, offs, cur_, NN);
    scatter_kernel<<<EE / 256, 256, 0, stream>>>(src, dst, ew, cur_, csr_src, csr_w);

    // 10 power iterations, ping-pong zA <-> zB (ends in zA == d_out)
    const float* cur = zA;
    float* nxt = zB;
    for (int it = 0; it < 10; ++it) {
        propagate_kernel<<<(NN * 64) / 256, 256, 0, stream>>>(cur, z0, nxt, offs, csr_src, csr_w);
        float* t = (float*)cur; cur = nxt; nxt = t;
    }

    // log_softmax in place on d_out
    logsoftmax_kernel<<<(NN * 64) / 256, 256, 0, stream>>>((float*)cur);
}

// Round 2
// 1846.460 us; speedup vs baseline: 1.1571x; 1.1571x over previous
//
#include <hip/hip_runtime.h>

#define NN     100000
#define EE     3200000
#define NF     512
#define HIDN   64
#define NCLS   64
#define ALPHA  0.1f

#define CHUNK  512                      // elements per scan block
#define NB     196                      // ceil(NN / CHUNK)

// ---------------------------------------------------------------------------
// Tiled fp32 GEMM: C[nrows x 64] = act(A[nrows x K] @ B[K x 64])
// 64x64 tile per block, BK=16, 256 threads, 4x4 micro-tile, float4 LDS reads.
// ---------------------------------------------------------------------------
template <bool RELU, bool DUP>
__global__ __launch_bounds__(256) void gemm_kernel(
    const float* __restrict__ A, const float* __restrict__ B,
    float* __restrict__ C, float* __restrict__ C2, int nrows, int K)
{
    const int BK = 16;
    __shared__ float AsT[BK][68];
    __shared__ float Bs [BK][68];

    int tid = threadIdx.x;
    int tx  = tid & 15;
    int ty  = tid >> 4;
    int rowBase = blockIdx.x * 64;

    int arow = tid >> 2;
    int ak   = (tid & 3) * 4;
    int brow = tid >> 4;
    int bcol = (tid & 15) * 4;

    float acc[4][4] = {};

    for (int k0 = 0; k0 < K; k0 += BK) {
        float4 av;
        int gr = rowBase + arow;
        if (gr < nrows) av = *(const float4*)(A + (size_t)gr * K + k0 + ak);
        else            av = make_float4(0.f, 0.f, 0.f, 0.f);
        float4 bv = *(const float4*)(B + (size_t)(k0 + brow) * 64 + bcol);

        __syncthreads();
        AsT[ak + 0][arow] = av.x;
        AsT[ak + 1][arow] = av.y;
        AsT[ak + 2][arow] = av.z;
        AsT[ak + 3][arow] = av.w;
        *(float4*)&Bs[brow][bcol] = bv;
        __syncthreads();

#pragma unroll
        for (int kk = 0; kk < BK; ++kk) {
            float4 a = *(const float4*)&AsT[kk][ty * 4];
            float4 b = *(const float4*)&Bs [kk][tx * 4];
            acc[0][0] = fmaf(a.x, b.x, acc[0][0]);
            acc[0][1] = fmaf(a.x, b.y, acc[0][1]);
            acc[0][2] = fmaf(a.x, b.z, acc[0][2]);
            acc[0][3] = fmaf(a.x, b.w, acc[0][3]);
            acc[1][0] = fmaf(a.y, b.x, acc[1][0]);
            acc[1][1] = fmaf(a.y, b.y, acc[1][1]);
            acc[1][2] = fmaf(a.y, b.z, acc[1][2]);
            acc[1][3] = fmaf(a.y, b.w, acc[1][3]);
            acc[2][0] = fmaf(a.z, b.x, acc[2][0]);
            acc[2][1] = fmaf(a.z, b.y, acc[2][1]);
            acc[2][2] = fmaf(a.z, b.z, acc[2][2]);
            acc[2][3] = fmaf(a.z, b.w, acc[2][3]);
            acc[3][0] = fmaf(a.w, b.x, acc[3][0]);
            acc[3][1] = fmaf(a.w, b.y, acc[3][1]);
            acc[3][2] = fmaf(a.w, b.z, acc[3][2]);
            acc[3][3] = fmaf(a.w, b.w, acc[3][3]);
        }
    }

#pragma unroll
    for (int i = 0; i < 4; ++i) {
        int r = rowBase + ty * 4 + i;
        if (r < nrows) {
            float4 o;
            o.x = acc[i][0]; o.y = acc[i][1]; o.z = acc[i][2]; o.w = acc[i][3];
            if (RELU) {
                o.x = fmaxf(o.x, 0.f); o.y = fmaxf(o.y, 0.f);
                o.z = fmaxf(o.z, 0.f); o.w = fmaxf(o.w, 0.f);
            }
            *(float4*)(C + (size_t)r * 64 + tx * 4) = o;
            if (DUP) *(float4*)(C2 + (size_t)r * 64 + tx * 4) = o;
        }
    }
}

// ---------------------------------------------------------------------------
// CSR construction
// ---------------------------------------------------------------------------
__global__ __launch_bounds__(256) void zero_kernel(int* __restrict__ p, int n)
{
    int i = blockIdx.x * 256 + threadIdx.x;
    if (i < n) p[i] = 0;
}

__global__ __launch_bounds__(256) void count_kernel(const int* __restrict__ dst,
                                                    int* __restrict__ deg)
{
    int e = blockIdx.x * 256 + threadIdx.x;
    if (e < EE) atomicAdd(&deg[dst[e]], 1);
}

// Phase A: per-block (CHUNK elements) reduction of deg -> bsum[b]
__global__ __launch_bounds__(256) void scanA_kernel(const int* __restrict__ deg,
                                                    int* __restrict__ bsum)
{
    int b = blockIdx.x, t = threadIdx.x;
    int i = b * CHUNK + t * 2;
    int v = 0;
    if (i < NN)     v += deg[i];
    if (i + 1 < NN) v += deg[i + 1];
    __shared__ int sm[256];
    sm[t] = v;
    __syncthreads();
    for (int o = 128; o > 0; o >>= 1) {
        if (t < o) sm[t] += sm[t + o];
        __syncthreads();
    }
    if (t == 0) bsum[b] = sm[0];
}

// Phase B: single block scans NB block sums -> bbase[b] (exclusive)
__global__ __launch_bounds__(256) void scanB_kernel(const int* __restrict__ bsum,
                                                    int* __restrict__ bbase,
                                                    int* __restrict__ offs)
{
    int t = threadIdx.x;
    int v = (t < NB) ? bsum[t] : 0;
    __shared__ int sm[256];
    sm[t] = v;
    __syncthreads();
    for (int o = 1; o < 256; o <<= 1) {
        int u = (t >= o) ? sm[t - o] : 0;
        __syncthreads();
        sm[t] += u;
        __syncthreads();
    }
    if (t < NB) bbase[t] = sm[t] - v;   // exclusive prefix
    if (t == 0) offs[NN] = EE;          // total degree is the edge count
}

// Phase C: rescan each chunk with its base -> offs / cursor
__global__ __launch_bounds__(256) void scanC_kernel(const int* __restrict__ deg,
                                                    const int* __restrict__ bbase,
                                                    int* __restrict__ offs,
                                                    int* __restrict__ cursor)
{
    int b = blockIdx.x, t = threadIdx.x;
    int i0 = b * CHUNK + t * 2;
    int d0 = (i0 < NN)     ? deg[i0]     : 0;
    int d1 = (i0 + 1 < NN) ? deg[i0 + 1] : 0;
    int local = d0 + d1;
    __shared__ int sm[256];
    sm[t] = local;
    __syncthreads();
    for (int o = 1; o < 256; o <<= 1) {
        int u = (t >= o) ? sm[t - o] : 0;
        __syncthreads();
        sm[t] += u;
        __syncthreads();
    }
    int excl = sm[t] - local + bbase[b];
    if (i0 < NN)     { offs[i0]     = excl;      cursor[i0]     = excl;      }
    if (i0 + 1 < NN) { offs[i0 + 1] = excl + d0; cursor[i0 + 1] = excl + d0; }
}

__global__ __launch_bounds__(256) void scatter_kernel(
    const int* __restrict__ src, const int* __restrict__ dst,
    const float* __restrict__ w, int* cursor, int2* __restrict__ csr)
{
    int e = blockIdx.x * 256 + threadIdx.x;
    if (e >= EE) return;
    int d = dst[e];
    int pos = atomicAdd(&cursor[d], 1);
    csr[pos] = make_int2(src[e], __float_as_int(w[e]));
}

// ---------------------------------------------------------------------------
// APPNP propagation: one wave per dst node, lane = class.
// z_new[n] = sum_{e in in(n)} w_e * z[src_e] + alpha * z0[n]
// LSM: fuse final log_softmax into the write.
// ---------------------------------------------------------------------------
template <bool LSM>
__global__ __launch_bounds__(256) void propagate_kernel(
    const float* __restrict__ zin, const float* __restrict__ z0,
    float* __restrict__ zout, const int* __restrict__ offs,
    const int2* __restrict__ csr)
{
    int gid  = blockIdx.x * 256 + threadIdx.x;
    int node = gid >> 6;
    int lane = gid & 63;
    if (node >= NN) return;

    int beg = offs[node];
    int end = offs[node + 1];
    float acc = 0.f;
    int j = beg;
    for (; j + 4 <= end; j += 4) {
        int2 e0 = csr[j],     e1 = csr[j + 1];
        int2 e2 = csr[j + 2], e3 = csr[j + 3];
        float v0 = zin[(size_t)e0.x * 64 + lane];
        float v1 = zin[(size_t)e1.x * 64 + lane];
        float v2 = zin[(size_t)e2.x * 64 + lane];
        float v3 = zin[(size_t)e3.x * 64 + lane];
        acc = fmaf(__int_as_float(e0.y), v0, acc);
        acc = fmaf(__int_as_float(e1.y), v1, acc);
        acc = fmaf(__int_as_float(e2.y), v2, acc);
        acc = fmaf(__int_as_float(e3.y), v3, acc);
    }
    for (; j < end; ++j) {
        int2 e = csr[j];
        acc = fmaf(__int_as_float(e.y), zin[(size_t)e.x * 64 + lane], acc);
    }

    float out = fmaf(ALPHA, z0[(size_t)node * 64 + lane], acc);

    if (LSM) {
        float m = out;
#pragma unroll
        for (int o = 32; o > 0; o >>= 1) m = fmaxf(m, __shfl_xor(m, o, 64));
        float e = __expf(out - m);
        float s = e;
#pragma unroll
        for (int o = 32; o > 0; o >>= 1) s += __shfl_xor(s, o, 64);
        out = (out - m) - __logf(s);
    }
    zout[(size_t)node * 64 + lane] = out;
}

// ---------------------------------------------------------------------------
extern "C" void kernel_launch(void* const* d_in, const int* in_sizes, int n_in,
                              void* d_out, int out_size, void* d_ws, size_t ws_size,
                              hipStream_t stream)
{
    const float* x  = (const float*)d_in[0];
    const int*   ei = (const int*)  d_in[1];
    const float* ew = (const float*)d_in[2];
    const float* W1 = (const float*)d_in[3];
    const float* W2 = (const float*)d_in[4];
    const int* src = ei;        // edge_index[0]
    const int* dst = ei + EE;   // edge_index[1]

    char* ws = (char*)d_ws;
    size_t off = 0;
    auto alloc = [&](size_t bytes) -> char* {
        char* p = ws + off;
        off += (bytes + 255) & ~(size_t)255;
        return p;
    };

    float* h     = (float*)alloc((size_t)NN * HIDN * 4);  // 25.6 MB; reused as CSR
    float* z0    = (float*)alloc((size_t)NN * NCLS * 4);
    float* zB    = (float*)alloc((size_t)NN * NCLS * 4);
    int*   deg   = (int*)  alloc((size_t)NN * 4);
    int*   offs  = (int*)  alloc((size_t)(NN + 1) * 4);
    int*   cur_  = (int*)  alloc((size_t)NN * 4);
    int*   bsum  = (int*)  alloc((size_t)NB * 4);
    int*   bbase = (int*)  alloc((size_t)NB * 4);

    int2* csr = (int2*)h;                                  // aliases h (dead after GEMM2)
    float* zA = (float*)d_out;

    // h = relu(x @ W1)
    gemm_kernel<true, false><<<(NN + 63) / 64, 256, 0, stream>>>(x, W1, h, nullptr, NN, NF);
    // z0 = h @ W2 ; z = z0
    gemm_kernel<false, true><<<(NN + 63) / 64, 256, 0, stream>>>(h, W2, z0, zA, NN, HIDN);

    // CSR by dst (h dead from here; csr aliases it)
    zero_kernel<<<(NN + 255) / 256, 256, 0, stream>>>(deg, NN);
    count_kernel<<<EE / 256, 256, 0, stream>>>(dst, deg);
    scanA_kernel<<<NB, 256, 0, stream>>>(deg, bsum);
    scanB_kernel<<<1, 256, 0, stream>>>(bsum, bbase, offs);
    scanC_kernel<<<NB, 256, 0, stream>>>(deg, bbase, offs, cur_);
    scatter_kernel<<<EE / 256, 256, 0, stream>>>(src, dst, ew, cur_, csr);

    // 10 power iterations, ping-pong zA <-> zB; iter 9 writes zA == d_out
    const float* cur = zA;
    float* nxt = zB;
    for (int it = 0; it < 10; ++it) {
        if (it < 9)
            propagate_kernel<false><<<(NN * 64) / 256, 256, 0, stream>>>(cur, z0, nxt, offs, csr);
        else
            propagate_kernel<true ><<<(NN * 64) / 256, 256, 0, stream>>>(cur, z0, nxt, offs, csr);
        float* t = (float*)cur; cur = nxt; nxt = t;
    }
}